// Round 1
// baseline (356.629 us; speedup 1.0000x reference)
//
#include <hip/hip_runtime.h>
#include <hip/hip_bf16.h>

#define NB 8
#define NC 128
#define NT 4096
#define NS 1024

typedef short bf16x8 __attribute__((ext_vector_type(8)));
typedef float f32x4  __attribute__((ext_vector_type(4)));

#define MFMA16(a, b, c) __builtin_amdgcn_mfma_f32_16x16x32_bf16(a, b, c, 0, 0, 0)

__device__ __forceinline__ short f2b(float x) {
    __hip_bfloat16 h = __float2bfloat16(x);
    return *reinterpret_cast<short*>(&h);
}

// ---------------------------------------------------------------------------
// Pack complex weights into doubled-K (256) bf16 matrices, row = out col d',
// col = k.  Q/K: [256][256]: rows<128 (real out): [Wr | -Wi]; rows>=128 (imag
// out): [Wi | Wr].  V (real out only): [128][256] = [Wvr | -Wvi].
// ---------------------------------------------------------------------------
__global__ __launch_bounds__(256) void pack_w_kernel(
    const float* __restrict__ Wqr, const float* __restrict__ Wqi,
    const float* __restrict__ Wkr, const float* __restrict__ Wki,
    const float* __restrict__ Wvr, const float* __restrict__ Wvi,
    __hip_bfloat16* __restrict__ WqT, __hip_bfloat16* __restrict__ WkT,
    __hip_bfloat16* __restrict__ WvT)
{
    const int idx = blockIdx.x * 256 + threadIdx.x;   // 640 blocks = 163840
    const float *Wr, *Wi; __hip_bfloat16* dst; int base;
    if (idx < 65536)       { Wr = Wqr; Wi = Wqi; dst = WqT; base = idx; }
    else if (idx < 131072) { Wr = Wkr; Wi = Wki; dst = WkT; base = idx - 65536; }
    else                   { Wr = Wvr; Wi = Wvi; dst = WvT; base = idx - 131072; }
    const int dp = base >> 8, k = base & 255;
    const int d  = dp & 127;
    float v;
    if (dp < 128) v = (k < 128) ? Wr[d * 128 + k] : -Wi[d * 128 + k - 128];
    else          v = (k < 128) ? Wi[d * 128 + k] :  Wr[d * 128 + k - 128];
    dst[base] = __float2bfloat16(v);
}

// ---------------------------------------------------------------------------
// Merged K + V projection.  32-source-row tiles -> 256 blocks (full CU
// coverage).  Waves split output columns: wave pair g=0 -> K cols 0..191,
// g=1 -> K cols 192..255 + all 128 V cols.  K written [b*NS+n][256]; V (real
// part) written TRANSPOSED VrT[b][d][m] via an LDS stash.
// ---------------------------------------------------------------------------
__global__ __launch_bounds__(256) void projKV_kernel(
    const float* __restrict__ Xr, const float* __restrict__ Xi,
    const __hip_bfloat16* __restrict__ WkT, const __hip_bfloat16* __restrict__ WvT,
    const float* __restrict__ bkr, const float* __restrict__ bki,
    const float* __restrict__ bvr,
    __hip_bfloat16* __restrict__ Kh, __hip_bfloat16* __restrict__ VrT)
{
    __shared__ __align__(16) char smem[27136];   // As[32][528] + Vstash[128][80]
    const int b   = blockIdx.x & 7;              // batch -> XCD affinity
    const int n0  = (blockIdx.x >> 3) * 32;
    const int tid = threadIdx.x;

    for (int i = tid; i < 32 * 64; i += 256) {
        const int cp = i >> 5, n = i & 31, c = cp * 2;
        const size_t rb = (size_t)(b * NC + c) * NS + n0 + n;
        const unsigned pr = (unsigned short)f2b(Xr[rb]) |
                            ((unsigned)(unsigned short)f2b(Xr[rb + NS]) << 16);
        const unsigned pi = (unsigned short)f2b(Xi[rb]) |
                            ((unsigned)(unsigned short)f2b(Xi[rb + NS]) << 16);
        *(unsigned*)(smem + n * 528 + c * 2)         = pr;
        *(unsigned*)(smem + n * 528 + (128 + c) * 2) = pi;
    }
    __syncthreads();

    const int w = tid >> 6, l15 = tid & 15, q = (tid & 63) >> 4;
    const int r0 = (w & 1) * 16;                 // rows within 32-row tile
    const int g  = w >> 1;                       // column group

    const char* wp[12];
    #pragma unroll
    for (int jj = 0; jj < 12; ++jj) {
        const int j = g * 12 + jj;               // global col tile 0..23
        wp[jj] = (j < 16)
            ? (const char*)WkT + (size_t)(j * 16 + l15) * 512 + q * 16
            : (const char*)WvT + (size_t)((j - 16) * 16 + l15) * 512 + q * 16;
    }

    f32x4 acc[12];
    #pragma unroll
    for (int jj = 0; jj < 12; ++jj) { acc[jj][0]=0.f; acc[jj][1]=0.f; acc[jj][2]=0.f; acc[jj][3]=0.f; }

    #pragma unroll
    for (int t = 0; t < 8; ++t) {
        const bf16x8 af = *(const bf16x8*)(smem + (r0 + l15) * 528 + (t * 32 + q * 8) * 2);
        #pragma unroll
        for (int jj = 0; jj < 12; ++jj) {
            const bf16x8 bf = *(const bf16x8*)(wp[jj] + t * 64);
            acc[jj] = MFMA16(af, bf, acc[jj]);
        }
    }

    #pragma unroll
    for (int jj = 0; jj < 12; ++jj) {
        const int j = g * 12 + jj;
        if (j < 16) {                            // K epilogue: direct global
            const int col = j * 16 + l15;
            const float bv = (col < 128) ? bkr[col] : bki[col - 128];
            #pragma unroll
            for (int r = 0; r < 4; ++r) {
                const int n = n0 + r0 + q * 4 + r;
                Kh[((size_t)(b * NS + n) << 8) + col] = __float2bfloat16(acc[jj][r] + bv);
            }
        } else {                                 // V epilogue: LDS transpose stash
            const int d = (j - 16) * 16 + l15;
            #pragma unroll
            for (int r = 0; r < 4; ++r)
                *(__hip_bfloat16*)(smem + 16896 + d * 80 + (r0 + q * 4 + r) * 2) =
                    __float2bfloat16(acc[jj][r] + bvr[d]);
        }
    }
    __syncthreads();
    for (int i = tid; i < 128 * 4; i += 256) {
        const int d = i >> 2, seg = i & 3;
        const int4 v = *(const int4*)(smem + 16896 + d * 80 + seg * 16);
        *(int4*)((char*)VrT + ((size_t)(b * NC + d) * NS + n0) * 2 + seg * 16) = v;
    }
}

// ---------------------------------------------------------------------------
// Flash attention with INLINE Q projection.  Block = batch b x 64 target rows.
// K/V fragments are read DIRECTLY from global (L2-resident with batch->XCD
// affinity): no K/V LDS staging, and since the P buffer is wave-private the
// 16-chunk main loop has ZERO barriers — waves run fully decoupled.
// ---------------------------------------------------------------------------
__global__ __launch_bounds__(256, 2) void attn_mfma_kernel(
    const float* __restrict__ tr_g, const float* __restrict__ ti_g,
    const __hip_bfloat16* __restrict__ WqT,
    const float* __restrict__ bqr, const float* __restrict__ bqi,
    const __hip_bfloat16* __restrict__ Kh, const __hip_bfloat16* __restrict__ VrT,
    const float* __restrict__ gamma_p, float* __restrict__ out)
{
    __shared__ __align__(16) char smem[43008];
    char* ks = smem;            // 64 x 528B : target tile -> Q-hat; later Of
    char* ps = smem + 33792;    // 4 waves x 16 x 144B: P, wave-private

    const int b    = blockIdx.x & 7;             // batch -> XCD affinity
    const int n0   = (blockIdx.x >> 3) * 64;
    const int tid  = threadIdx.x;
    const int w    = tid >> 6, l15 = tid & 15, q = (tid & 63) >> 4;
    const int row0 = w * 16;
    char* psw = ps + w * 2304;

    // ---- stage target tile As[n][c] (64 x 256 bf16) into ks ----
    for (int i = tid; i < 64 * 64; i += 256) {
        const int cp = i >> 6, n = i & 63, c = cp * 2;
        const size_t rb = (size_t)(b * NC + c) * NT + n0 + n;
        const unsigned pr = (unsigned short)f2b(tr_g[rb]) |
                            ((unsigned)(unsigned short)f2b(tr_g[rb + NT]) << 16);
        const unsigned pi = (unsigned short)f2b(ti_g[rb]) |
                            ((unsigned)(unsigned short)f2b(ti_g[rb + NT]) << 16);
        *(unsigned*)(ks + n * 528 + c * 2)         = pr;
        *(unsigned*)(ks + n * 528 + (128 + c) * 2) = pi;
    }
    __syncthreads();

    // ---- inline Q projection: rows row0..row0+15 x 256 cols ----
    {
        f32x4 qacc[16];
        #pragma unroll
        for (int j = 0; j < 16; ++j) { qacc[j][0]=0.f; qacc[j][1]=0.f; qacc[j][2]=0.f; qacc[j][3]=0.f; }
        #pragma unroll
        for (int t = 0; t < 8; ++t) {
            const bf16x8 af = *(const bf16x8*)(ks + (row0 + l15) * 528 + (t * 32 + q * 8) * 2);
            #pragma unroll
            for (int j = 0; j < 16; ++j) {
                const int col = j * 16 + l15;
                const bf16x8 bf = *(const bf16x8*)((const char*)WqT + col * 512 + (t * 32 + q * 8) * 2);
                qacc[j] = MFMA16(af, bf, qacc[j]);
            }
        }
        __syncthreads();                     // all waves done reading As
        const float inv_s = 0.08838834764831845f;   // 1/sqrt(128)
        #pragma unroll
        for (int j = 0; j < 16; ++j) {
            const int col  = j * 16 + l15;
            const float bv = (col < 128) ? bqr[col] : bqi[col - 128];
            #pragma unroll
            for (int r = 0; r < 4; ++r) {
                const int row = row0 + q * 4 + r;
                *(__hip_bfloat16*)(ks + row * 528 + col * 2) =
                    __float2bfloat16((qacc[j][r] + bv) * inv_s);
            }
        }
    }
    __syncthreads();

    bf16x8 qf[8];
    #pragma unroll
    for (int t = 0; t < 8; ++t)
        qf[t] = *(const bf16x8*)(ks + (row0 + l15) * 528 + (t * 32 + q * 8) * 2);

    f32x4 oacc[8];
    #pragma unroll
    for (int j = 0; j < 8; ++j) { oacc[j][0]=0.f; oacc[j][1]=0.f; oacc[j][2]=0.f; oacc[j][3]=0.f; }
    float m_run[4] = {-1e30f, -1e30f, -1e30f, -1e30f};
    float l_run[4] = {0.f, 0.f, 0.f, 0.f};

    // per-thread K/V row pointers; chunk offset folded in by increments.
    const char* kp[4];
    #pragma unroll
    for (int j = 0; j < 4; ++j)
        kp[j] = (const char*)Kh + ((size_t)(b * NS + j * 16 + l15) << 9) + q * 16;
    const char* vp[8];
    #pragma unroll
    for (int j = 0; j < 8; ++j)
        vp[j] = (const char*)VrT + (size_t)(b * NC + j * 16 + l15) * (NS * 2) + q * 16;

    #pragma unroll 1
    for (int ch = 0; ch < 16; ++ch) {
        // ---- QK^T: fragments straight from L2 ----
        f32x4 s[4];
        #pragma unroll
        for (int j = 0; j < 4; ++j) { s[j][0]=0.f; s[j][1]=0.f; s[j][2]=0.f; s[j][3]=0.f; }
        #pragma unroll
        for (int t = 0; t < 8; ++t) {
            #pragma unroll
            for (int j = 0; j < 4; ++j) {
                const bf16x8 kf = *(const bf16x8*)(kp[j] + t * 64);
                s[j] = MFMA16(qf[t], kf, s[j]);
            }
        }

        // ---- online softmax (wave-local, 16-lane groups) ----
        float alpha_r[4];
        #pragma unroll
        for (int r = 0; r < 4; ++r) {
            float mx = fmaxf(fmaxf(s[0][r], s[1][r]), fmaxf(s[2][r], s[3][r]));
            #pragma unroll
            for (int off = 8; off >= 1; off >>= 1)
                mx = fmaxf(mx, __shfl_xor(mx, off, 16));
            const float mn = fmaxf(m_run[r], mx);
            const float a  = __expf(m_run[r] - mn);
            m_run[r] = mn; alpha_r[r] = a;
            float sum = 0.f;
            #pragma unroll
            for (int j = 0; j < 4; ++j) {
                const float p = __expf(s[j][r] - mn);
                s[j][r] = p; sum += p;
            }
            #pragma unroll
            for (int off = 8; off >= 1; off >>= 1)
                sum += __shfl_xor(sum, off, 16);
            l_run[r] = l_run[r] * a + sum;
        }

        // ---- P -> LDS (wave-private: no barrier, lgkmcnt orders it) ----
        #pragma unroll
        for (int j = 0; j < 4; ++j) {
            #pragma unroll
            for (int r = 0; r < 4; ++r)
                *(__hip_bfloat16*)(psw + (q * 4 + r) * 144 + (j * 16 + l15) * 2) =
                    __float2bfloat16(s[j][r]);
        }

        #pragma unroll
        for (int j = 0; j < 8; ++j) {
            #pragma unroll
            for (int r = 0; r < 4; ++r) oacc[j][r] *= alpha_r[r];
        }
        // ---- PV: V fragments straight from L2 ----
        #pragma unroll
        for (int t2 = 0; t2 < 2; ++t2) {
            const bf16x8 pf = *(const bf16x8*)(psw + l15 * 144 + (t2 * 32 + q * 8) * 2);
            #pragma unroll
            for (int j = 0; j < 8; ++j) {
                const bf16x8 vf = *(const bf16x8*)(vp[j] + t2 * 64);
                oacc[j] = MFMA16(pf, vf, oacc[j]);
            }
        }

        #pragma unroll
        for (int j = 0; j < 4; ++j) kp[j] += 64 * 512;   // next 64 source rows
        #pragma unroll
        for (int j = 0; j < 8; ++j) vp[j] += 64 * 2;     // next 64 source cols
    }

    __syncthreads();
    float* Of = (float*)smem;                // 128 x 65 f32 (reuse; < ps base)
    const float g = gamma_p[0];
    #pragma unroll
    for (int r = 0; r < 4; ++r) {
        const float inv_l = g / fmaxf(l_run[r], 1e-30f);
        const int m = row0 + q * 4 + r;
        #pragma unroll
        for (int j = 0; j < 8; ++j)
            Of[(j * 16 + l15) * 65 + m] = oacc[j][r] * inv_l;
    }
    __syncthreads();
    float* ob = out + (size_t)b * NC * NT + n0;
    for (int i = tid; i < 128 * 64; i += 256) {
        const int d = i >> 6, m = i & 63;
        ob[(size_t)d * NT + m] = Of[d * 65 + m];
    }
}

// ---------------------------------------------------------------------------
extern "C" void kernel_launch(void* const* d_in, const int* in_sizes, int n_in,
                              void* d_out, int out_size, void* d_ws, size_t ws_size,
                              hipStream_t stream)
{
    const float* target_r = (const float*)d_in[0];
    const float* target_i = (const float*)d_in[1];
    const float* source_r = (const float*)d_in[2];
    const float* source_i = (const float*)d_in[3];
    const float* Wq_r = (const float*)d_in[4];
    const float* Wq_i = (const float*)d_in[5];
    const float* bq_r = (const float*)d_in[6];
    const float* bq_i = (const float*)d_in[7];
    const float* Wk_r = (const float*)d_in[8];
    const float* Wk_i = (const float*)d_in[9];
    const float* bk_r = (const float*)d_in[10];
    const float* bk_i = (const float*)d_in[11];
    const float* Wv_r = (const float*)d_in[12];
    const float* Wv_i = (const float*)d_in[13];
    const float* bv_r = (const float*)d_in[14];
    const float* bv_i = (const float*)d_in[15];
    const float* gamma = (const float*)d_in[16];

    // workspace carve (bytes) — total 6.62 MB
    char* ws = (char*)d_ws;
    __hip_bfloat16* Kh  = (__hip_bfloat16*)(ws);                    // 4,194,304
    __hip_bfloat16* VrT = (__hip_bfloat16*)(ws + 4194304);          // 2,097,152
    __hip_bfloat16* WqT = (__hip_bfloat16*)(ws + 6291456);          //   131,072
    __hip_bfloat16* WkT = (__hip_bfloat16*)(ws + 6422528);          //   131,072
    __hip_bfloat16* WvT = (__hip_bfloat16*)(ws + 6553600);          //    65,536

    pack_w_kernel<<<640, 256, 0, stream>>>(Wq_r, Wq_i, Wk_r, Wk_i, Wv_r, Wv_i,
                                           WqT, WkT, WvT);

    projKV_kernel<<<NB * (NS / 32), 256, 0, stream>>>(
        source_r, source_i, WkT, WvT, bk_r, bk_i, bv_r, Kh, VrT);

    attn_mfma_kernel<<<NB * (NT / 64), 256, 0, stream>>>(
        target_r, target_i, WqT, bq_r, bq_i, Kh, VrT, gamma, (float*)d_out);
}

// Round 2
// 228.597 us; speedup vs baseline: 1.5601x; 1.5601x over previous
//
#include <hip/hip_runtime.h>
#include <hip/hip_bf16.h>

#define NB 8
#define NC 128
#define NT 4096
#define NS 1024

typedef short bf16x8 __attribute__((ext_vector_type(8)));
typedef float f32x4  __attribute__((ext_vector_type(4)));

#define MFMA16(a, b, c) __builtin_amdgcn_mfma_f32_16x16x32_bf16(a, b, c, 0, 0, 0)

__device__ __forceinline__ short f2b(float x) {
    __hip_bfloat16 h = __float2bfloat16(x);
    return *reinterpret_cast<short*>(&h);
}

// async global->LDS, 16B per lane; dest = wave-uniform base + lane*16 (linear)
__device__ __forceinline__ void gl_lds16(const void* g, void* l) {
    __builtin_amdgcn_global_load_lds(
        (const __attribute__((address_space(1))) unsigned int*)g,
        (__attribute__((address_space(3))) unsigned int*)l, 16, 0, 0);
}

// ---------------------------------------------------------------------------
// Pack complex weights into doubled-K (256) bf16 matrices, row = out col d',
// col = k.  Q/K: [256][256]: rows<128 (real out): [Wr | -Wi]; rows>=128 (imag
// out): [Wi | Wr].  V (real out only): [128][256] = [Wvr | -Wvi].
// ---------------------------------------------------------------------------
__global__ __launch_bounds__(256) void pack_w_kernel(
    const float* __restrict__ Wqr, const float* __restrict__ Wqi,
    const float* __restrict__ Wkr, const float* __restrict__ Wki,
    const float* __restrict__ Wvr, const float* __restrict__ Wvi,
    __hip_bfloat16* __restrict__ WqT, __hip_bfloat16* __restrict__ WkT,
    __hip_bfloat16* __restrict__ WvT)
{
    const int idx = blockIdx.x * 256 + threadIdx.x;   // 640 blocks = 163840
    const float *Wr, *Wi; __hip_bfloat16* dst; int base;
    if (idx < 65536)       { Wr = Wqr; Wi = Wqi; dst = WqT; base = idx; }
    else if (idx < 131072) { Wr = Wkr; Wi = Wki; dst = WkT; base = idx - 65536; }
    else                   { Wr = Wvr; Wi = Wvi; dst = WvT; base = idx - 131072; }
    const int dp = base >> 8, k = base & 255;
    const int d  = dp & 127;
    float v;
    if (dp < 128) v = (k < 128) ? Wr[d * 128 + k] : -Wi[d * 128 + k - 128];
    else          v = (k < 128) ? Wi[d * 128 + k] :  Wr[d * 128 + k - 128];
    dst[base] = __float2bfloat16(v);
}

// ---------------------------------------------------------------------------
// Merged K + V projection.  32-source-row tiles -> 256 blocks.
// ---------------------------------------------------------------------------
__global__ __launch_bounds__(256) void projKV_kernel(
    const float* __restrict__ Xr, const float* __restrict__ Xi,
    const __hip_bfloat16* __restrict__ WkT, const __hip_bfloat16* __restrict__ WvT,
    const float* __restrict__ bkr, const float* __restrict__ bki,
    const float* __restrict__ bvr,
    __hip_bfloat16* __restrict__ Kh, __hip_bfloat16* __restrict__ VrT)
{
    __shared__ __align__(16) char smem[27136];   // As[32][528] + Vstash[128][80]
    const int b   = blockIdx.x & 7;              // batch -> XCD affinity
    const int n0  = (blockIdx.x >> 3) * 32;
    const int tid = threadIdx.x;

    for (int i = tid; i < 32 * 64; i += 256) {
        const int cp = i >> 5, n = i & 31, c = cp * 2;
        const size_t rb = (size_t)(b * NC + c) * NS + n0 + n;
        const unsigned pr = (unsigned short)f2b(Xr[rb]) |
                            ((unsigned)(unsigned short)f2b(Xr[rb + NS]) << 16);
        const unsigned pi = (unsigned short)f2b(Xi[rb]) |
                            ((unsigned)(unsigned short)f2b(Xi[rb + NS]) << 16);
        *(unsigned*)(smem + n * 528 + c * 2)         = pr;
        *(unsigned*)(smem + n * 528 + (128 + c) * 2) = pi;
    }
    __syncthreads();

    const int w = tid >> 6, l15 = tid & 15, q = (tid & 63) >> 4;
    const int r0 = (w & 1) * 16;                 // rows within 32-row tile
    const int g  = w >> 1;                       // column group

    const char* wp[12];
    #pragma unroll
    for (int jj = 0; jj < 12; ++jj) {
        const int j = g * 12 + jj;               // global col tile 0..23
        wp[jj] = (j < 16)
            ? (const char*)WkT + (size_t)(j * 16 + l15) * 512 + q * 16
            : (const char*)WvT + (size_t)((j - 16) * 16 + l15) * 512 + q * 16;
    }

    f32x4 acc[12];
    #pragma unroll
    for (int jj = 0; jj < 12; ++jj) { acc[jj][0]=0.f; acc[jj][1]=0.f; acc[jj][2]=0.f; acc[jj][3]=0.f; }

    #pragma unroll
    for (int t = 0; t < 8; ++t) {
        const bf16x8 af = *(const bf16x8*)(smem + (r0 + l15) * 528 + (t * 32 + q * 8) * 2);
        #pragma unroll
        for (int jj = 0; jj < 12; ++jj) {
            const bf16x8 bf = *(const bf16x8*)(wp[jj] + t * 64);
            acc[jj] = MFMA16(af, bf, acc[jj]);
        }
    }

    #pragma unroll
    for (int jj = 0; jj < 12; ++jj) {
        const int j = g * 12 + jj;
        if (j < 16) {                            // K epilogue: direct global
            const int col = j * 16 + l15;
            const float bv = (col < 128) ? bkr[col] : bki[col - 128];
            #pragma unroll
            for (int r = 0; r < 4; ++r) {
                const int n = n0 + r0 + q * 4 + r;
                Kh[((size_t)(b * NS + n) << 8) + col] = __float2bfloat16(acc[jj][r] + bv);
            }
        } else {                                 // V epilogue: LDS transpose stash
            const int d = (j - 16) * 16 + l15;
            #pragma unroll
            for (int r = 0; r < 4; ++r)
                *(__hip_bfloat16*)(smem + 16896 + d * 80 + (r0 + q * 4 + r) * 2) =
                    __float2bfloat16(acc[jj][r] + bvr[d]);
        }
    }
    __syncthreads();
    for (int i = tid; i < 128 * 4; i += 256) {
        const int d = i >> 2, seg = i & 3;
        const int4 v = *(const int4*)(smem + 16896 + d * 80 + seg * 16);
        *(int4*)((char*)VrT + ((size_t)(b * NC + d) * NS + n0) * 2 + seg * 16) = v;
    }
}

// ---------------------------------------------------------------------------
// Flash attention, inline Q projection.  Block = batch b x 64 target rows.
// 32-source-row chunks, K double-buffered in LDS via global_load_lds with
// both-sides XOR swizzle; V prefetched to registers; ONE barrier per chunk.
// ---------------------------------------------------------------------------
__global__ __launch_bounds__(256, 2) void attn_mfma_kernel(
    const float* __restrict__ tr_g, const float* __restrict__ ti_g,
    const __hip_bfloat16* __restrict__ WqT,
    const float* __restrict__ bqr, const float* __restrict__ bqi,
    const __hip_bfloat16* __restrict__ Kh, const __hip_bfloat16* __restrict__ VrT,
    const float* __restrict__ gamma_p, float* __restrict__ out)
{
    __shared__ __align__(16) char smem[71680];
    char* As  = smem;            // 64 x 528B: target tile -> Q-hat; later Of
    char* kb0 = smem + 33792;    // K chunk buf 0: 32 rows x 512B (linear, swz)
    char* kb1 = smem + 50176;    // K chunk buf 1
    char* ps  = smem + 66560;    // 4 waves x 16 x 80B: P, wave-private

    const int b    = blockIdx.x & 7;             // batch -> XCD affinity
    const int n0   = (blockIdx.x >> 3) * 64;
    const int tid  = threadIdx.x;
    const int w    = tid >> 6, lane = tid & 63, l15 = tid & 15, q = (tid & 63) >> 4;
    const int row0 = w * 16;
    char* psw = ps + w * 1280;

    // ---- stage target tile As[n][c] (64 x 256 bf16) ----
    for (int i = tid; i < 64 * 64; i += 256) {
        const int cp = i >> 6, n = i & 63, c = cp * 2;
        const size_t rb = (size_t)(b * NC + c) * NT + n0 + n;
        const unsigned pr = (unsigned short)f2b(tr_g[rb]) |
                            ((unsigned)(unsigned short)f2b(tr_g[rb + NT]) << 16);
        const unsigned pi = (unsigned short)f2b(ti_g[rb]) |
                            ((unsigned)(unsigned short)f2b(ti_g[rb + NT]) << 16);
        *(unsigned*)(As + n * 528 + c * 2)         = pr;
        *(unsigned*)(As + n * 528 + (128 + c) * 2) = pi;
    }

    // ---- stage K chunk 0 (async; drained by the barriers below) ----
    const char* Kbase = (const char*)Kh + ((size_t)(b * NS) << 9);
    #pragma unroll
    for (int i = 0; i < 4; ++i) {
        const int ml = w * 8 + i * 2 + (lane >> 5);               // row 0..31
        const int so = ml * 512 + ((((lane & 31) ^ (ml & 7))) << 4);
        gl_lds16(Kbase + so, kb0 + (w * 4 + i) * 1024);
    }
    __syncthreads();

    // ---- inline Q projection: rows row0..row0+15 x 256 cols ----
    {
        f32x4 qacc[16];
        #pragma unroll
        for (int j = 0; j < 16; ++j) { qacc[j][0]=0.f; qacc[j][1]=0.f; qacc[j][2]=0.f; qacc[j][3]=0.f; }
        #pragma unroll
        for (int t = 0; t < 8; ++t) {
            const bf16x8 af = *(const bf16x8*)(As + (row0 + l15) * 528 + (t * 32 + q * 8) * 2);
            #pragma unroll
            for (int j = 0; j < 16; ++j) {
                const int col = j * 16 + l15;
                const bf16x8 bf = *(const bf16x8*)((const char*)WqT + col * 512 + (t * 32 + q * 8) * 2);
                qacc[j] = MFMA16(af, bf, qacc[j]);
            }
        }
        __syncthreads();
        const float inv_s = 0.08838834764831845f;   // 1/sqrt(128)
        #pragma unroll
        for (int j = 0; j < 16; ++j) {
            const int col  = j * 16 + l15;
            const float bv = (col < 128) ? bqr[col] : bqi[col - 128];
            #pragma unroll
            for (int r = 0; r < 4; ++r) {
                const int row = row0 + q * 4 + r;
                *(__hip_bfloat16*)(As + row * 528 + col * 2) =
                    __float2bfloat16((qacc[j][r] + bv) * inv_s);
            }
        }
    }
    __syncthreads();

    bf16x8 qf[8];
    #pragma unroll
    for (int t = 0; t < 8; ++t)
        qf[t] = *(const bf16x8*)(As + (row0 + l15) * 528 + (t * 32 + q * 8) * 2);

    f32x4 oacc[8];
    #pragma unroll
    for (int j = 0; j < 8; ++j) { oacc[j][0]=0.f; oacc[j][1]=0.f; oacc[j][2]=0.f; oacc[j][3]=0.f; }
    float m_run[4] = {-1e30f, -1e30f, -1e30f, -1e30f};
    float l_run[4] = {0.f, 0.f, 0.f, 0.f};

    // V row pointers (fragments read straight from L2 into regs)
    const char* vp[8];
    #pragma unroll
    for (int j = 0; j < 8; ++j)
        vp[j] = (const char*)VrT + (size_t)(b * NC + j * 16 + l15) * (NS * 2) + q * 16;

    // swizzled K read-offset components: slot' = ((t*4+q) ^ (l15&7))
    const int e3 = l15 & 7;
    const int qx = q ^ (e3 & 3);
    const int eh = e3 >> 2;

    char* kbc = kb0;
    char* kbn = kb1;

    #pragma unroll 1
    for (int ch = 0; ch < 32; ++ch) {
        // ---- V fragments for this chunk -> regs (latency covered by QK+SM) ----
        bf16x8 vfr[8];
        #pragma unroll
        for (int j = 0; j < 8; ++j) { vfr[j] = *(const bf16x8*)vp[j]; vp[j] += 64; }

        // ---- stage NEXT K chunk (drained only at end-of-iter barrier) ----
        const size_t sb = (size_t)((ch < 31 ? ch + 1 : 31) * 32) * 512;
        #pragma unroll
        for (int i = 0; i < 4; ++i) {
            const int ml = w * 8 + i * 2 + (lane >> 5);
            const int so = ml * 512 + ((((lane & 31) ^ (ml & 7))) << 4);
            gl_lds16(Kbase + sb + so, kbn + (w * 4 + i) * 1024);
        }

        // ---- QK^T from current K buffer (swizzled reads, b128 floor) ----
        f32x4 s0v, s1v;
        s0v[0]=0.f; s0v[1]=0.f; s0v[2]=0.f; s0v[3]=0.f;
        s1v[0]=0.f; s1v[1]=0.f; s1v[2]=0.f; s1v[3]=0.f;
        #pragma unroll
        for (int t = 0; t < 8; ++t) {
            const int tb = ((t ^ eh) << 6) + (qx << 4);
            const bf16x8 k0 = *(const bf16x8*)(kbc + l15 * 512 + tb);
            s0v = MFMA16(qf[t], k0, s0v);
            const bf16x8 k1 = *(const bf16x8*)(kbc + (16 + l15) * 512 + tb);
            s1v = MFMA16(qf[t], k1, s1v);
        }

        // ---- online softmax (wave-local, 16-lane groups) ----
        float alpha_r[4];
        #pragma unroll
        for (int r = 0; r < 4; ++r) {
            float mx = fmaxf(s0v[r], s1v[r]);
            #pragma unroll
            for (int off = 8; off >= 1; off >>= 1)
                mx = fmaxf(mx, __shfl_xor(mx, off, 16));
            const float mn = fmaxf(m_run[r], mx);
            const float a  = __expf(m_run[r] - mn);
            m_run[r] = mn; alpha_r[r] = a;
            const float p0 = __expf(s0v[r] - mn);
            const float p1 = __expf(s1v[r] - mn);
            s0v[r] = p0; s1v[r] = p1;
            float sum = p0 + p1;
            #pragma unroll
            for (int off = 8; off >= 1; off >>= 1)
                sum += __shfl_xor(sum, off, 16);
            l_run[r] = l_run[r] * a + sum;
        }

        // ---- P -> wave-private LDS (no barrier; lgkmcnt orders it) ----
        #pragma unroll
        for (int r = 0; r < 4; ++r) {
            *(__hip_bfloat16*)(psw + (q * 4 + r) * 80 + l15 * 2) =
                __float2bfloat16(s0v[r]);
            *(__hip_bfloat16*)(psw + (q * 4 + r) * 80 + (16 + l15) * 2) =
                __float2bfloat16(s1v[r]);
        }

        #pragma unroll
        for (int j = 0; j < 8; ++j) {
            #pragma unroll
            for (int r = 0; r < 4; ++r) oacc[j][r] *= alpha_r[r];
        }

        // ---- PV: P from LDS, V from prefetched regs ----
        const bf16x8 pf = *(const bf16x8*)(psw + l15 * 80 + q * 16);
        #pragma unroll
        for (int j = 0; j < 8; ++j)
            oacc[j] = MFMA16(pf, vfr[j], oacc[j]);

        // single barrier: next-chunk stage complete + this buffer reusable
        __syncthreads();
        char* tsw = kbc; kbc = kbn; kbn = tsw;
    }

    // ---- epilogue ----
    float* Of = (float*)smem;                // 128 x 65 f32 (reuse As region)
    const float g = gamma_p[0];
    #pragma unroll
    for (int r = 0; r < 4; ++r) {
        const float inv_l = g / fmaxf(l_run[r], 1e-30f);
        const int m = row0 + q * 4 + r;
        #pragma unroll
        for (int j = 0; j < 8; ++j)
            Of[(j * 16 + l15) * 65 + m] = oacc[j][r] * inv_l;
    }
    __syncthreads();
    float* ob = out + (size_t)b * NC * NT + n0;
    for (int i = tid; i < 128 * 64; i += 256) {
        const int d = i >> 6, m = i & 63;
        ob[(size_t)d * NT + m] = Of[d * 65 + m];
    }
}

// ---------------------------------------------------------------------------
extern "C" void kernel_launch(void* const* d_in, const int* in_sizes, int n_in,
                              void* d_out, int out_size, void* d_ws, size_t ws_size,
                              hipStream_t stream)
{
    const float* target_r = (const float*)d_in[0];
    const float* target_i = (const float*)d_in[1];
    const float* source_r = (const float*)d_in[2];
    const float* source_i = (const float*)d_in[3];
    const float* Wq_r = (const float*)d_in[4];
    const float* Wq_i = (const float*)d_in[5];
    const float* bq_r = (const float*)d_in[6];
    const float* bq_i = (const float*)d_in[7];
    const float* Wk_r = (const float*)d_in[8];
    const float* Wk_i = (const float*)d_in[9];
    const float* bk_r = (const float*)d_in[10];
    const float* bk_i = (const float*)d_in[11];
    const float* Wv_r = (const float*)d_in[12];
    const float* Wv_i = (const float*)d_in[13];
    const float* bv_r = (const float*)d_in[14];
    const float* bv_i = (const float*)d_in[15];
    const float* gamma = (const float*)d_in[16];

    // workspace carve (bytes) — total 6.62 MB
    char* ws = (char*)d_ws;
    __hip_bfloat16* Kh  = (__hip_bfloat16*)(ws);                    // 4,194,304
    __hip_bfloat16* VrT = (__hip_bfloat16*)(ws + 4194304);          // 2,097,152
    __hip_bfloat16* WqT = (__hip_bfloat16*)(ws + 6291456);          //   131,072
    __hip_bfloat16* WkT = (__hip_bfloat16*)(ws + 6422528);          //   131,072
    __hip_bfloat16* WvT = (__hip_bfloat16*)(ws + 6553600);          //    65,536

    pack_w_kernel<<<640, 256, 0, stream>>>(Wq_r, Wq_i, Wk_r, Wk_i, Wv_r, Wv_i,
                                           WqT, WkT, WvT);

    projKV_kernel<<<NB * (NS / 32), 256, 0, stream>>>(
        source_r, source_i, WkT, WvT, bk_r, bk_i, bv_r, Kh, VrT);

    attn_mfma_kernel<<<NB * (NT / 64), 256, 0, stream>>>(
        target_r, target_i, WqT, bq_r, bq_i, Kh, VrT, gamma, (float*)d_out);
}

// Round 3
// 222.130 us; speedup vs baseline: 1.6055x; 1.0291x over previous
//
#include <hip/hip_runtime.h>
#include <hip/hip_bf16.h>

#define NB 8
#define NC 128
#define NT 4096
#define NS 1024

typedef short bf16x8 __attribute__((ext_vector_type(8)));
typedef float f32x4  __attribute__((ext_vector_type(4)));

#define MFMA16(a, b, c) __builtin_amdgcn_mfma_f32_16x16x32_bf16(a, b, c, 0, 0, 0)

__device__ __forceinline__ short f2b(float x) {
    __hip_bfloat16 h = __float2bfloat16(x);
    return *reinterpret_cast<short*>(&h);
}

// async global->LDS, 16B per lane; dest = wave-uniform base + lane*16 (linear)
__device__ __forceinline__ void gl_lds16(const void* g, void* l) {
    __builtin_amdgcn_global_load_lds(
        (const __attribute__((address_space(1))) unsigned int*)g,
        (__attribute__((address_space(3))) unsigned int*)l, 16, 0, 0);
}

// ---------------------------------------------------------------------------
// Pack complex weights into doubled-K (256) bf16 matrices, row = out col d',
// col = k.  Q/K: [256][256]: rows<128 (real out): [Wr | -Wi]; rows>=128 (imag
// out): [Wi | Wr].  V (real out only): [128][256] = [Wvr | -Wvi].
// ---------------------------------------------------------------------------
__global__ __launch_bounds__(256) void pack_w_kernel(
    const float* __restrict__ Wqr, const float* __restrict__ Wqi,
    const float* __restrict__ Wkr, const float* __restrict__ Wki,
    const float* __restrict__ Wvr, const float* __restrict__ Wvi,
    __hip_bfloat16* __restrict__ WqT, __hip_bfloat16* __restrict__ WkT,
    __hip_bfloat16* __restrict__ WvT)
{
    const int idx = blockIdx.x * 256 + threadIdx.x;   // 640 blocks = 163840
    const float *Wr, *Wi; __hip_bfloat16* dst; int base;
    if (idx < 65536)       { Wr = Wqr; Wi = Wqi; dst = WqT; base = idx; }
    else if (idx < 131072) { Wr = Wkr; Wi = Wki; dst = WkT; base = idx - 65536; }
    else                   { Wr = Wvr; Wi = Wvi; dst = WvT; base = idx - 131072; }
    const int dp = base >> 8, k = base & 255;
    const int d  = dp & 127;
    float v;
    if (dp < 128) v = (k < 128) ? Wr[d * 128 + k] : -Wi[d * 128 + k - 128];
    else          v = (k < 128) ? Wi[d * 128 + k] :  Wr[d * 128 + k - 128];
    dst[base] = __float2bfloat16(v);
}

// ---------------------------------------------------------------------------
// Merged K + V projection.  32-source-row tiles -> 256 blocks.
// ---------------------------------------------------------------------------
__global__ __launch_bounds__(256) void projKV_kernel(
    const float* __restrict__ Xr, const float* __restrict__ Xi,
    const __hip_bfloat16* __restrict__ WkT, const __hip_bfloat16* __restrict__ WvT,
    const float* __restrict__ bkr, const float* __restrict__ bki,
    const float* __restrict__ bvr,
    __hip_bfloat16* __restrict__ Kh, __hip_bfloat16* __restrict__ VrT)
{
    __shared__ __align__(16) char smem[27136];   // As[32][528] + Vstash[128][80]
    const int b   = blockIdx.x & 7;              // batch -> XCD affinity
    const int n0  = (blockIdx.x >> 3) * 32;
    const int tid = threadIdx.x;

    for (int i = tid; i < 32 * 64; i += 256) {
        const int cp = i >> 5, n = i & 31, c = cp * 2;
        const size_t rb = (size_t)(b * NC + c) * NS + n0 + n;
        const unsigned pr = (unsigned short)f2b(Xr[rb]) |
                            ((unsigned)(unsigned short)f2b(Xr[rb + NS]) << 16);
        const unsigned pi = (unsigned short)f2b(Xi[rb]) |
                            ((unsigned)(unsigned short)f2b(Xi[rb + NS]) << 16);
        *(unsigned*)(smem + n * 528 + c * 2)         = pr;
        *(unsigned*)(smem + n * 528 + (128 + c) * 2) = pi;
    }
    __syncthreads();

    const int w = tid >> 6, l15 = tid & 15, q = (tid & 63) >> 4;
    const int r0 = (w & 1) * 16;                 // rows within 32-row tile
    const int g  = w >> 1;                       // column group

    const char* wp[12];
    #pragma unroll
    for (int jj = 0; jj < 12; ++jj) {
        const int j = g * 12 + jj;               // global col tile 0..23
        wp[jj] = (j < 16)
            ? (const char*)WkT + (size_t)(j * 16 + l15) * 512 + q * 16
            : (const char*)WvT + (size_t)((j - 16) * 16 + l15) * 512 + q * 16;
    }

    f32x4 acc[12];
    #pragma unroll
    for (int jj = 0; jj < 12; ++jj) { acc[jj][0]=0.f; acc[jj][1]=0.f; acc[jj][2]=0.f; acc[jj][3]=0.f; }

    #pragma unroll
    for (int t = 0; t < 8; ++t) {
        const bf16x8 af = *(const bf16x8*)(smem + (r0 + l15) * 528 + (t * 32 + q * 8) * 2);
        #pragma unroll
        for (int jj = 0; jj < 12; ++jj) {
            const bf16x8 bf = *(const bf16x8*)(wp[jj] + t * 64);
            acc[jj] = MFMA16(af, bf, acc[jj]);
        }
    }

    #pragma unroll
    for (int jj = 0; jj < 12; ++jj) {
        const int j = g * 12 + jj;
        if (j < 16) {                            // K epilogue: direct global
            const int col = j * 16 + l15;
            const float bv = (col < 128) ? bkr[col] : bki[col - 128];
            #pragma unroll
            for (int r = 0; r < 4; ++r) {
                const int n = n0 + r0 + q * 4 + r;
                Kh[((size_t)(b * NS + n) << 8) + col] = __float2bfloat16(acc[jj][r] + bv);
            }
        } else {                                 // V epilogue: LDS transpose stash
            const int d = (j - 16) * 16 + l15;
            #pragma unroll
            for (int r = 0; r < 4; ++r)
                *(__hip_bfloat16*)(smem + 16896 + d * 80 + (r0 + q * 4 + r) * 2) =
                    __float2bfloat16(acc[jj][r] + bvr[d]);
        }
    }
    __syncthreads();
    for (int i = tid; i < 128 * 4; i += 256) {
        const int d = i >> 2, seg = i & 3;
        const int4 v = *(const int4*)(smem + 16896 + d * 80 + seg * 16);
        *(int4*)((char*)VrT + ((size_t)(b * NC + d) * NS + n0) * 2 + seg * 16) = v;
    }
}

// ---------------------------------------------------------------------------
// Stage one 32-source-row chunk (K 16KB + V 8KB) into LDS buffer `buf`.
// K rows swizzled: LDS slot s of row ml holds global slot s ^ (ml&7).
// V rows swizzled: LDS slot s of row d holds global slot s ^ (d&3).
// All via global_load_lds (linear dest, pre-swizzled source; rule 21).
// ---------------------------------------------------------------------------
__device__ __forceinline__ void stage_chunk(const char* Kbase, const char* Vbase,
                                            char* buf, int ch, int w, int lane)
{
    const char* ks = Kbase + (size_t)ch * 16384;
    #pragma unroll
    for (int i = 0; i < 4; ++i) {
        const int ml = w * 8 + i * 2 + (lane >> 5);          // K row 0..31
        const int so = ml * 512 + (((lane & 31) ^ (ml & 7)) << 4);
        gl_lds16(ks + so, buf + (w * 4 + i) * 1024);
    }
    const char* vsrc = Vbase + (size_t)ch * 64;
    #pragma unroll
    for (int i = 0; i < 2; ++i) {
        const int d  = (w + i * 4) * 16 + (lane >> 2);       // V row 0..127
        const int so = d * 2048 + (((lane & 3) ^ ((lane >> 2) & 3)) << 4);
        gl_lds16(vsrc + so, buf + 16384 + (w + i * 4) * 1024);
    }
}

// ---------------------------------------------------------------------------
// Flash attention, inline Q projection.  Block = batch b x 64 target rows.
// 32-row chunks, K+V triple-buffered in LDS, staged 2 chunks ahead via
// global_load_lds; counted s_waitcnt vmcnt(6) + RAW s_barrier per chunk —
// the pipeline is never drained to vmcnt(0) inside the loop (T3+T4).
// ---------------------------------------------------------------------------
__global__ __launch_bounds__(256, 2) void attn_mfma_kernel(
    const float* __restrict__ tr_g, const float* __restrict__ ti_g,
    const __hip_bfloat16* __restrict__ WqT,
    const float* __restrict__ bqr, const float* __restrict__ bqi,
    const __hip_bfloat16* __restrict__ Kh, const __hip_bfloat16* __restrict__ VrT,
    const float* __restrict__ gamma_p, float* __restrict__ out)
{
    __shared__ __align__(16) char smem[78848];
    // [0, 73728): 3 x 24576 chunk buffers (K 16KB + V 8KB each).
    // Prologue overlays As[64][528] = 33792 B on the same region.
    // [73728, 78848): P, 4 waves x 1280 B, wave-private.
    char* As = smem;
    char* ps = smem + 73728;

    const int b    = blockIdx.x & 7;             // batch -> XCD affinity
    const int n0   = (blockIdx.x >> 3) * 64;
    const int tid  = threadIdx.x;
    const int w    = tid >> 6, lane = tid & 63, l15 = tid & 15, q = (tid & 63) >> 4;
    const int row0 = w * 16;
    char* psw = ps + w * 1280;

    // ---- stage target tile As[n][c] (64 x 256 bf16) ----
    for (int i = tid; i < 64 * 64; i += 256) {
        const int cp = i >> 6, n = i & 63, c = cp * 2;
        const size_t rb = (size_t)(b * NC + c) * NT + n0 + n;
        const unsigned pr = (unsigned short)f2b(tr_g[rb]) |
                            ((unsigned)(unsigned short)f2b(tr_g[rb + NT]) << 16);
        const unsigned pi = (unsigned short)f2b(ti_g[rb]) |
                            ((unsigned)(unsigned short)f2b(ti_g[rb + NT]) << 16);
        *(unsigned*)(As + n * 528 + c * 2)         = pr;
        *(unsigned*)(As + n * 528 + (128 + c) * 2) = pi;
    }
    __syncthreads();

    // ---- inline Q projection (fully wave-private: own 16 rows only) ----
    bf16x8 qf[8];
    {
        f32x4 qacc[16];
        #pragma unroll
        for (int j = 0; j < 16; ++j) { qacc[j][0]=0.f; qacc[j][1]=0.f; qacc[j][2]=0.f; qacc[j][3]=0.f; }
        #pragma unroll
        for (int t = 0; t < 8; ++t) {
            const bf16x8 af = *(const bf16x8*)(As + (row0 + l15) * 528 + (t * 32 + q * 8) * 2);
            #pragma unroll
            for (int j = 0; j < 16; ++j) {
                const int col = j * 16 + l15;
                const bf16x8 bf = *(const bf16x8*)((const char*)WqT + col * 512 + (t * 32 + q * 8) * 2);
                qacc[j] = MFMA16(af, bf, qacc[j]);
            }
        }
        const float inv_s = 0.08838834764831845f;   // 1/sqrt(128)
        #pragma unroll
        for (int j = 0; j < 16; ++j) {
            const int col  = j * 16 + l15;
            const float bv = (col < 128) ? bqr[col] : bqi[col - 128];
            #pragma unroll
            for (int r = 0; r < 4; ++r) {
                const int row = row0 + q * 4 + r;
                *(__hip_bfloat16*)(As + row * 528 + col * 2) =
                    __float2bfloat16((qacc[j][r] + bv) * inv_s);
            }
        }
        #pragma unroll
        for (int t = 0; t < 8; ++t)
            qf[t] = *(const bf16x8*)(As + (row0 + l15) * 528 + (t * 32 + q * 8) * 2);
    }
    __syncthreads();        // all waves hold qf; As region free for buffers

    const char* Kbase = (const char*)Kh + ((size_t)(b * NS) << 9);
    const char* Vbase = (const char*)VrT + (size_t)b * NC * NS * 2;
    char* bA = smem;                 // current chunk
    char* bB = smem + 24576;         // chunk+1 (in flight)
    char* bC = smem + 49152;         // chunk+2 (staged this iter)

    stage_chunk(Kbase, Vbase, bA, 0, w, lane);   // 6 loads
    stage_chunk(Kbase, Vbase, bB, 1, w, lane);   // 12 outstanding

    f32x4 oacc[8];
    #pragma unroll
    for (int j = 0; j < 8; ++j) { oacc[j][0]=0.f; oacc[j][1]=0.f; oacc[j][2]=0.f; oacc[j][3]=0.f; }
    float m_run[4] = {-1e30f, -1e30f, -1e30f, -1e30f};
    float l_run[4] = {0.f, 0.f, 0.f, 0.f};

    // swizzled read-offset components
    const int e3   = l15 & 7;
    const int qx   = q ^ (e3 & 3);       // K slot low bits
    const int eh   = e3 >> 2;            // K slot high bit
    const int vswz = (q ^ (l15 & 3)) << 4;   // V slot

    #pragma unroll 1
    for (int ch = 0; ch < 32; ++ch) {
        // retire exactly this chunk's 6 loads; chunk+1 stays in flight
        asm volatile("s_waitcnt vmcnt(6)" ::: "memory");
        __builtin_amdgcn_s_barrier();    // raw: no vmcnt(0) drain

        // stage chunk+2 (re-stage 31 on tail iters to keep vmcnt invariant)
        const int sch = (ch + 2 < 32) ? ch + 2 : 31;
        stage_chunk(Kbase, Vbase, bC, sch, w, lane);

        // ---- QK^T from current K buffer (swizzled reads) ----
        f32x4 s0v, s1v;
        s0v[0]=0.f; s0v[1]=0.f; s0v[2]=0.f; s0v[3]=0.f;
        s1v[0]=0.f; s1v[1]=0.f; s1v[2]=0.f; s1v[3]=0.f;
        #pragma unroll
        for (int t = 0; t < 8; ++t) {
            const int tb = ((t ^ eh) << 6) + (qx << 4);
            const bf16x8 k0 = *(const bf16x8*)(bA + l15 * 512 + tb);
            s0v = MFMA16(qf[t], k0, s0v);
            const bf16x8 k1 = *(const bf16x8*)(bA + (16 + l15) * 512 + tb);
            s1v = MFMA16(qf[t], k1, s1v);
        }

        // ---- online softmax (wave-local, 16-lane groups) ----
        float alpha_r[4];
        #pragma unroll
        for (int r = 0; r < 4; ++r) {
            float mx = fmaxf(s0v[r], s1v[r]);
            #pragma unroll
            for (int off = 8; off >= 1; off >>= 1)
                mx = fmaxf(mx, __shfl_xor(mx, off, 16));
            const float mn = fmaxf(m_run[r], mx);
            const float a  = __expf(m_run[r] - mn);
            m_run[r] = mn; alpha_r[r] = a;
            const float p0 = __expf(s0v[r] - mn);
            const float p1 = __expf(s1v[r] - mn);
            s0v[r] = p0; s1v[r] = p1;
            float sum = p0 + p1;
            #pragma unroll
            for (int off = 8; off >= 1; off >>= 1)
                sum += __shfl_xor(sum, off, 16);
            l_run[r] = l_run[r] * a + sum;
        }

        // ---- P -> wave-private LDS (no barrier; lgkmcnt orders it) ----
        #pragma unroll
        for (int r = 0; r < 4; ++r) {
            *(__hip_bfloat16*)(psw + (q * 4 + r) * 80 + l15 * 2) =
                __float2bfloat16(s0v[r]);
            *(__hip_bfloat16*)(psw + (q * 4 + r) * 80 + (16 + l15) * 2) =
                __float2bfloat16(s1v[r]);
        }

        #pragma unroll
        for (int j = 0; j < 8; ++j) {
            #pragma unroll
            for (int r = 0; r < 4; ++r) oacc[j][r] *= alpha_r[r];
        }

        // ---- PV: P from LDS, V from staged LDS (swizzled) ----
        const bf16x8 pf = *(const bf16x8*)(psw + l15 * 80 + q * 16);
        #pragma unroll
        for (int j = 0; j < 8; ++j) {
            const bf16x8 vf = *(const bf16x8*)(bA + 16384 + (j * 16 + l15) * 64 + vswz);
            oacc[j] = MFMA16(pf, vf, oacc[j]);
        }

        char* t0 = bA; bA = bB; bB = bC; bC = t0;   // rotate buffers
    }

    // ---- epilogue ----
    __syncthreads();                         // drains remaining staging
    float* Of = (float*)smem;                // 128 x 65 f32 (reuse buffers)
    const float g = gamma_p[0];
    #pragma unroll
    for (int r = 0; r < 4; ++r) {
        const float inv_l = g / fmaxf(l_run[r], 1e-30f);
        const int m = row0 + q * 4 + r;
        #pragma unroll
        for (int j = 0; j < 8; ++j)
            Of[(j * 16 + l15) * 65 + m] = oacc[j][r] * inv_l;
    }
    __syncthreads();
    float* ob = out + (size_t)b * NC * NT + n0;
    for (int i = tid; i < 128 * 64; i += 256) {
        const int d = i >> 6, m = i & 63;
        ob[(size_t)d * NT + m] = Of[d * 65 + m];
    }
}

// ---------------------------------------------------------------------------
extern "C" void kernel_launch(void* const* d_in, const int* in_sizes, int n_in,
                              void* d_out, int out_size, void* d_ws, size_t ws_size,
                              hipStream_t stream)
{
    const float* target_r = (const float*)d_in[0];
    const float* target_i = (const float*)d_in[1];
    const float* source_r = (const float*)d_in[2];
    const float* source_i = (const float*)d_in[3];
    const float* Wq_r = (const float*)d_in[4];
    const float* Wq_i = (const float*)d_in[5];
    const float* bq_r = (const float*)d_in[6];
    const float* bq_i = (const float*)d_in[7];
    const float* Wk_r = (const float*)d_in[8];
    const float* Wk_i = (const float*)d_in[9];
    const float* bk_r = (const float*)d_in[10];
    const float* bk_i = (const float*)d_in[11];
    const float* Wv_r = (const float*)d_in[12];
    const float* Wv_i = (const float*)d_in[13];
    const float* bv_r = (const float*)d_in[14];
    const float* bv_i = (const float*)d_in[15];
    const float* gamma = (const float*)d_in[16];

    // workspace carve (bytes) — total 6.62 MB
    char* ws = (char*)d_ws;
    __hip_bfloat16* Kh  = (__hip_bfloat16*)(ws);                    // 4,194,304
    __hip_bfloat16* VrT = (__hip_bfloat16*)(ws + 4194304);          // 2,097,152
    __hip_bfloat16* WqT = (__hip_bfloat16*)(ws + 6291456);          //   131,072
    __hip_bfloat16* WkT = (__hip_bfloat16*)(ws + 6422528);          //   131,072
    __hip_bfloat16* WvT = (__hip_bfloat16*)(ws + 6553600);          //    65,536

    pack_w_kernel<<<640, 256, 0, stream>>>(Wq_r, Wq_i, Wk_r, Wk_i, Wv_r, Wv_i,
                                           WqT, WkT, WvT);

    projKV_kernel<<<NB * (NS / 32), 256, 0, stream>>>(
        source_r, source_i, WkT, WvT, bk_r, bk_i, bv_r, Kh, VrT);

    attn_mfma_kernel<<<NB * (NT / 64), 256, 0, stream>>>(
        target_r, target_i, WqT, bq_r, bq_i, Kh, VrT, gamma, (float*)d_out);
}

// Round 4
// 198.289 us; speedup vs baseline: 1.7985x; 1.1202x over previous
//
#include <hip/hip_runtime.h>
#include <hip/hip_bf16.h>

#define NB 8
#define NC 128
#define NT 4096
#define NS 1024

typedef short bf16x8 __attribute__((ext_vector_type(8)));
typedef float f32x4  __attribute__((ext_vector_type(4)));

#define MFMA16(a, b, c) __builtin_amdgcn_mfma_f32_16x16x32_bf16(a, b, c, 0, 0, 0)

__device__ __forceinline__ short f2b(float x) {
    __hip_bfloat16 h = __float2bfloat16(x);
    return *reinterpret_cast<short*>(&h);
}

// async global->LDS, 16B per lane; dest = wave-uniform base + lane*16 (linear)
__device__ __forceinline__ void gl_lds16(const void* g, void* l) {
    __builtin_amdgcn_global_load_lds(
        (const __attribute__((address_space(1))) unsigned int*)g,
        (__attribute__((address_space(3))) unsigned int*)l, 16, 0, 0);
}

// ---------------------------------------------------------------------------
// Pack complex weights into doubled-K (256) bf16 matrices, row = out col d',
// col = k.  Q/K: [256][256]: rows<128 (real out): [Wr | -Wi]; rows>=128 (imag
// out): [Wi | Wr].  V (real out only): [128][256] = [Wvr | -Wvi].
// ---------------------------------------------------------------------------
__global__ __launch_bounds__(256) void pack_w_kernel(
    const float* __restrict__ Wqr, const float* __restrict__ Wqi,
    const float* __restrict__ Wkr, const float* __restrict__ Wki,
    const float* __restrict__ Wvr, const float* __restrict__ Wvi,
    __hip_bfloat16* __restrict__ WqT, __hip_bfloat16* __restrict__ WkT,
    __hip_bfloat16* __restrict__ WvT)
{
    const int idx = blockIdx.x * 256 + threadIdx.x;   // 640 blocks = 163840
    const float *Wr, *Wi; __hip_bfloat16* dst; int base;
    if (idx < 65536)       { Wr = Wqr; Wi = Wqi; dst = WqT; base = idx; }
    else if (idx < 131072) { Wr = Wkr; Wi = Wki; dst = WkT; base = idx - 65536; }
    else                   { Wr = Wvr; Wi = Wvi; dst = WvT; base = idx - 131072; }
    const int dp = base >> 8, k = base & 255;
    const int d  = dp & 127;
    float v;
    if (dp < 128) v = (k < 128) ? Wr[d * 128 + k] : -Wi[d * 128 + k - 128];
    else          v = (k < 128) ? Wi[d * 128 + k] :  Wr[d * 128 + k - 128];
    dst[base] = __float2bfloat16(v);
}

// ---------------------------------------------------------------------------
// Merged K + V projection.  32-source-row tiles -> 256 blocks.
// ---------------------------------------------------------------------------
__global__ __launch_bounds__(256) void projKV_kernel(
    const float* __restrict__ Xr, const float* __restrict__ Xi,
    const __hip_bfloat16* __restrict__ WkT, const __hip_bfloat16* __restrict__ WvT,
    const float* __restrict__ bkr, const float* __restrict__ bki,
    const float* __restrict__ bvr,
    __hip_bfloat16* __restrict__ Kh, __hip_bfloat16* __restrict__ VrT)
{
    __shared__ __align__(16) char smem[27136];   // As[32][528] + Vstash[128][80]
    const int b   = blockIdx.x & 7;              // batch -> XCD affinity
    const int n0  = (blockIdx.x >> 3) * 32;
    const int tid = threadIdx.x;

    for (int i = tid; i < 32 * 64; i += 256) {
        const int cp = i >> 5, n = i & 31, c = cp * 2;
        const size_t rb = (size_t)(b * NC + c) * NS + n0 + n;
        const unsigned pr = (unsigned short)f2b(Xr[rb]) |
                            ((unsigned)(unsigned short)f2b(Xr[rb + NS]) << 16);
        const unsigned pi = (unsigned short)f2b(Xi[rb]) |
                            ((unsigned)(unsigned short)f2b(Xi[rb + NS]) << 16);
        *(unsigned*)(smem + n * 528 + c * 2)         = pr;
        *(unsigned*)(smem + n * 528 + (128 + c) * 2) = pi;
    }
    __syncthreads();

    const int w = tid >> 6, l15 = tid & 15, q = (tid & 63) >> 4;
    const int r0 = (w & 1) * 16;                 // rows within 32-row tile
    const int g  = w >> 1;                       // column group

    const char* wp[12];
    #pragma unroll
    for (int jj = 0; jj < 12; ++jj) {
        const int j = g * 12 + jj;               // global col tile 0..23
        wp[jj] = (j < 16)
            ? (const char*)WkT + (size_t)(j * 16 + l15) * 512 + q * 16
            : (const char*)WvT + (size_t)((j - 16) * 16 + l15) * 512 + q * 16;
    }

    f32x4 acc[12];
    #pragma unroll
    for (int jj = 0; jj < 12; ++jj) { acc[jj][0]=0.f; acc[jj][1]=0.f; acc[jj][2]=0.f; acc[jj][3]=0.f; }

    #pragma unroll
    for (int t = 0; t < 8; ++t) {
        const bf16x8 af = *(const bf16x8*)(smem + (r0 + l15) * 528 + (t * 32 + q * 8) * 2);
        #pragma unroll
        for (int jj = 0; jj < 12; ++jj) {
            const bf16x8 bf = *(const bf16x8*)(wp[jj] + t * 64);
            acc[jj] = MFMA16(af, bf, acc[jj]);
        }
    }

    #pragma unroll
    for (int jj = 0; jj < 12; ++jj) {
        const int j = g * 12 + jj;
        if (j < 16) {                            // K epilogue: direct global
            const int col = j * 16 + l15;
            const float bv = (col < 128) ? bkr[col] : bki[col - 128];
            #pragma unroll
            for (int r = 0; r < 4; ++r) {
                const int n = n0 + r0 + q * 4 + r;
                Kh[((size_t)(b * NS + n) << 8) + col] = __float2bfloat16(acc[jj][r] + bv);
            }
        } else {                                 // V epilogue: LDS transpose stash
            const int d = (j - 16) * 16 + l15;
            #pragma unroll
            for (int r = 0; r < 4; ++r)
                *(__hip_bfloat16*)(smem + 16896 + d * 80 + (r0 + q * 4 + r) * 2) =
                    __float2bfloat16(acc[jj][r] + bvr[d]);
        }
    }
    __syncthreads();
    for (int i = tid; i < 128 * 4; i += 256) {
        const int d = i >> 2, seg = i & 3;
        const int4 v = *(const int4*)(smem + 16896 + d * 80 + seg * 16);
        *(int4*)((char*)VrT + ((size_t)(b * NC + d) * NS + n0) * 2 + seg * 16) = v;
    }
}

// ---------------------------------------------------------------------------
// Stage one 32-source-row chunk (K 16KB + V 8KB) into LDS buffer `buf`.
// K rows swizzled: LDS slot s of row ml holds global slot s ^ (ml&7).
// V rows swizzled: LDS slot s of row d holds global slot s ^ (d&3).
// All via global_load_lds (linear dest, pre-swizzled source; rule 21).
// ---------------------------------------------------------------------------
__device__ __forceinline__ void stage_chunk(const char* Kbase, const char* Vbase,
                                            char* buf, int ch, int w, int lane)
{
    const char* ks = Kbase + (size_t)ch * 16384;
    #pragma unroll
    for (int i = 0; i < 4; ++i) {
        const int ml = w * 8 + i * 2 + (lane >> 5);          // K row 0..31
        const int so = ml * 512 + (((lane & 31) ^ (ml & 7)) << 4);
        gl_lds16(ks + so, buf + (w * 4 + i) * 1024);
    }
    const char* vsrc = Vbase + (size_t)ch * 64;
    #pragma unroll
    for (int i = 0; i < 2; ++i) {
        const int d  = (w + i * 4) * 16 + (lane >> 2);       // V row 0..127
        const int so = d * 2048 + (((lane & 3) ^ ((lane >> 2) & 3)) << 4);
        gl_lds16(vsrc + so, buf + 16384 + (w + i * 4) * 1024);
    }
}

// ---------------------------------------------------------------------------
// Flash attention, inline Q projection.  Block = batch b x 64 target rows.
// Scores are structurally bounded (|S| <~ 15), so NO online softmax:
// p = exp2(S * log2e/sqrt(C)) directly (scale folded into Q-hat), and the
// denominator l = sum_k p rides the matrix pipe via a ones-column MFMA.
// The chunk loop has zero cross-lane shuffles and zero rescale work.
// K+V triple-buffered in LDS, staged 2 ahead, counted vmcnt(6) + raw
// s_barrier per chunk (never drained to 0 in the loop).
// ---------------------------------------------------------------------------
__global__ __launch_bounds__(256, 2) void attn_mfma_kernel(
    const float* __restrict__ tr_g, const float* __restrict__ ti_g,
    const __hip_bfloat16* __restrict__ WqT,
    const float* __restrict__ bqr, const float* __restrict__ bqi,
    const __hip_bfloat16* __restrict__ Kh, const __hip_bfloat16* __restrict__ VrT,
    const float* __restrict__ gamma_p, float* __restrict__ out)
{
    __shared__ __align__(16) char smem[78848];
    // [0, 73728): 3 x 24576 chunk buffers (K 16KB + V 8KB each).
    // Prologue overlays As[64][528] = 33792 B on the same region.
    // [73728, 78848): P, 4 waves x 1280 B, wave-private.
    char* As = smem;
    char* ps = smem + 73728;

    const int b    = blockIdx.x & 7;             // batch -> XCD affinity
    const int n0   = (blockIdx.x >> 3) * 64;
    const int tid  = threadIdx.x;
    const int w    = tid >> 6, lane = tid & 63, l15 = tid & 15, q = (tid & 63) >> 4;
    const int row0 = w * 16;
    char* psw = ps + w * 1280;

    // ---- stage target tile As[n][c] (64 x 256 bf16) ----
    for (int i = tid; i < 64 * 64; i += 256) {
        const int cp = i >> 6, n = i & 63, c = cp * 2;
        const size_t rb = (size_t)(b * NC + c) * NT + n0 + n;
        const unsigned pr = (unsigned short)f2b(tr_g[rb]) |
                            ((unsigned)(unsigned short)f2b(tr_g[rb + NT]) << 16);
        const unsigned pi = (unsigned short)f2b(ti_g[rb]) |
                            ((unsigned)(unsigned short)f2b(ti_g[rb + NT]) << 16);
        *(unsigned*)(As + n * 528 + c * 2)         = pr;
        *(unsigned*)(As + n * 528 + (128 + c) * 2) = pi;
    }
    __syncthreads();

    // ---- inline Q projection (wave-private rows); scale = log2e/sqrt(C) ----
    bf16x8 qf[8];
    {
        f32x4 qacc[16];
        #pragma unroll
        for (int j = 0; j < 16; ++j) { qacc[j][0]=0.f; qacc[j][1]=0.f; qacc[j][2]=0.f; qacc[j][3]=0.f; }
        #pragma unroll
        for (int t = 0; t < 8; ++t) {
            const bf16x8 af = *(const bf16x8*)(As + (row0 + l15) * 528 + (t * 32 + q * 8) * 2);
            #pragma unroll
            for (int j = 0; j < 16; ++j) {
                const int col = j * 16 + l15;
                const bf16x8 bf = *(const bf16x8*)((const char*)WqT + col * 512 + (t * 32 + q * 8) * 2);
                qacc[j] = MFMA16(af, bf, qacc[j]);
            }
        }
        const float inv_s = 0.12751744f;         // log2(e) / sqrt(128)
        #pragma unroll
        for (int j = 0; j < 16; ++j) {
            const int col  = j * 16 + l15;
            const float bv = (col < 128) ? bqr[col] : bqi[col - 128];
            #pragma unroll
            for (int r = 0; r < 4; ++r) {
                const int row = row0 + q * 4 + r;
                *(__hip_bfloat16*)(As + row * 528 + col * 2) =
                    __float2bfloat16((qacc[j][r] + bv) * inv_s);
            }
        }
        #pragma unroll
        for (int t = 0; t < 8; ++t)
            qf[t] = *(const bf16x8*)(As + (row0 + l15) * 528 + (t * 32 + q * 8) * 2);
    }
    __syncthreads();        // all waves hold qf; As region free for buffers

    const char* Kbase = (const char*)Kh + ((size_t)(b * NS) << 9);
    const char* Vbase = (const char*)VrT + (size_t)b * NC * NS * 2;
    char* bA = smem;                 // current chunk
    char* bB = smem + 24576;         // chunk+1 (in flight)
    char* bC = smem + 49152;         // chunk+2 (staged this iter)

    stage_chunk(Kbase, Vbase, bA, 0, w, lane);   // 6 loads
    stage_chunk(Kbase, Vbase, bB, 1, w, lane);   // 12 outstanding

    f32x4 oacc[8];
    #pragma unroll
    for (int j = 0; j < 8; ++j) { oacc[j][0]=0.f; oacc[j][1]=0.f; oacc[j][2]=0.f; oacc[j][3]=0.f; }
    f32x4 lacc;                      // denominator: ones-column accumulator
    lacc[0]=0.f; lacc[1]=0.f; lacc[2]=0.f; lacc[3]=0.f;

    // B-fragment of the all-ones column: B row 0 (lanes l15==0) = 1.0bf16
    bf16x8 onesf;
    {
        const short ob = (l15 == 0) ? (short)0x3F80 : (short)0;
        #pragma unroll
        for (int e = 0; e < 8; ++e) onesf[e] = ob;
    }

    // swizzled read-offset components
    const int e3   = l15 & 7;
    const int qx   = q ^ (e3 & 3);       // K slot low bits
    const int eh   = e3 >> 2;            // K slot high bit
    const int vswz = (q ^ (l15 & 3)) << 4;   // V slot

    #pragma unroll 1
    for (int ch = 0; ch < 32; ++ch) {
        // retire exactly this chunk's 6 loads; chunk+1 stays in flight
        asm volatile("s_waitcnt vmcnt(6)" ::: "memory");
        __builtin_amdgcn_s_barrier();    // raw: no vmcnt(0) drain

        // stage chunk+2 (re-stage 31 on tail iters to keep vmcnt invariant)
        const int sch = (ch + 2 < 32) ? ch + 2 : 31;
        stage_chunk(Kbase, Vbase, bC, sch, w, lane);

        // ---- QK^T from current K buffer (swizzled reads) ----
        f32x4 s0v, s1v;
        s0v[0]=0.f; s0v[1]=0.f; s0v[2]=0.f; s0v[3]=0.f;
        s1v[0]=0.f; s1v[1]=0.f; s1v[2]=0.f; s1v[3]=0.f;
        #pragma unroll
        for (int t = 0; t < 8; ++t) {
            const int tb = ((t ^ eh) << 6) + (qx << 4);
            const bf16x8 k0 = *(const bf16x8*)(bA + l15 * 512 + tb);
            s0v = MFMA16(qf[t], k0, s0v);
            const bf16x8 k1 = *(const bf16x8*)(bA + (16 + l15) * 512 + tb);
            s1v = MFMA16(qf[t], k1, s1v);
        }

        // ---- p = 2^S' directly (no max, no cross-lane) ----
        #pragma unroll
        for (int r = 0; r < 4; ++r) {
            s0v[r] = exp2f(s0v[r]);
            s1v[r] = exp2f(s1v[r]);
        }

        // ---- P -> wave-private LDS (no barrier; lgkmcnt orders it) ----
        #pragma unroll
        for (int r = 0; r < 4; ++r) {
            *(__hip_bfloat16*)(psw + (q * 4 + r) * 80 + l15 * 2) =
                __float2bfloat16(s0v[r]);
            *(__hip_bfloat16*)(psw + (q * 4 + r) * 80 + (16 + l15) * 2) =
                __float2bfloat16(s1v[r]);
        }

        // ---- PV: P from LDS, V from staged LDS (swizzled); l via ones-col ----
        const bf16x8 pf = *(const bf16x8*)(psw + l15 * 80 + q * 16);
        lacc = MFMA16(pf, onesf, lacc);
        #pragma unroll
        for (int j = 0; j < 8; ++j) {
            const bf16x8 vf = *(const bf16x8*)(bA + 16384 + (j * 16 + l15) * 64 + vswz);
            oacc[j] = MFMA16(pf, vf, oacc[j]);
        }

        char* t0 = bA; bA = bB; bB = bC; bC = t0;   // rotate buffers
    }

    // ---- epilogue ----
    __syncthreads();                         // drains remaining staging
    float* Of = (float*)smem;                // 128 x 65 f32 (reuse buffers)
    const float g = gamma_p[0];
    #pragma unroll
    for (int r = 0; r < 4; ++r) {
        // l for my rows lives in lane (q*16) (l15==0 of my 16-lane group)
        const float lr = __shfl(lacc[r], q * 16, 64);
        const float inv_l = g / fmaxf(lr, 1e-30f);
        const int m = row0 + q * 4 + r;
        #pragma unroll
        for (int j = 0; j < 8; ++j)
            Of[(j * 16 + l15) * 65 + m] = oacc[j][r] * inv_l;
    }
    __syncthreads();
    float* ob = out + (size_t)b * NC * NT + n0;
    for (int i = tid; i < 128 * 64; i += 256) {
        const int d = i >> 6, m = i & 63;
        ob[(size_t)d * NT + m] = Of[d * 65 + m];
    }
}

// ---------------------------------------------------------------------------
extern "C" void kernel_launch(void* const* d_in, const int* in_sizes, int n_in,
                              void* d_out, int out_size, void* d_ws, size_t ws_size,
                              hipStream_t stream)
{
    const float* target_r = (const float*)d_in[0];
    const float* target_i = (const float*)d_in[1];
    const float* source_r = (const float*)d_in[2];
    const float* source_i = (const float*)d_in[3];
    const float* Wq_r = (const float*)d_in[4];
    const float* Wq_i = (const float*)d_in[5];
    const float* bq_r = (const float*)d_in[6];
    const float* bq_i = (const float*)d_in[7];
    const float* Wk_r = (const float*)d_in[8];
    const float* Wk_i = (const float*)d_in[9];
    const float* bk_r = (const float*)d_in[10];
    const float* bk_i = (const float*)d_in[11];
    const float* Wv_r = (const float*)d_in[12];
    const float* Wv_i = (const float*)d_in[13];
    const float* bv_r = (const float*)d_in[14];
    const float* bv_i = (const float*)d_in[15];
    const float* gamma = (const float*)d_in[16];

    // workspace carve (bytes) — total 6.62 MB
    char* ws = (char*)d_ws;
    __hip_bfloat16* Kh  = (__hip_bfloat16*)(ws);                    // 4,194,304
    __hip_bfloat16* VrT = (__hip_bfloat16*)(ws + 4194304);          // 2,097,152
    __hip_bfloat16* WqT = (__hip_bfloat16*)(ws + 6291456);          //   131,072
    __hip_bfloat16* WkT = (__hip_bfloat16*)(ws + 6422528);          //   131,072
    __hip_bfloat16* WvT = (__hip_bfloat16*)(ws + 6553600);          //    65,536

    pack_w_kernel<<<640, 256, 0, stream>>>(Wq_r, Wq_i, Wk_r, Wk_i, Wv_r, Wv_i,
                                           WqT, WkT, WvT);

    projKV_kernel<<<NB * (NS / 32), 256, 0, stream>>>(
        source_r, source_i, WkT, WvT, bk_r, bk_i, bv_r, Kh, VrT);

    attn_mfma_kernel<<<NB * (NT / 64), 256, 0, stream>>>(
        target_r, target_i, WqT, bq_r, bq_i, Kh, VrT, gamma, (float*)d_out);
}